// Round 1
// baseline (633.641 us; speedup 1.0000x reference)
//
#include <hip/hip_runtime.h>
#include <math.h>

// MoE gate: B=4, S=4096, H=2048, E=64, top-2, seq_aux loss.
// d_out layout (float): topk_idx [16384*2] | topk_weight [16384*2] | aux_loss [1]

#define TT 16384   // tokens
#define HH 2048
#define EE 64
#define BB 4
#define SS 4096
#define M_TOK 32   // tokens per block
#define KC 512     // k-range per wave (2048 / 4 waves)

// K0: transpose weight [E][H] -> Wt[H][E] so lane=expert reads are coalesced.
__global__ void transpose_w(const float* __restrict__ w, float* __restrict__ wt) {
    int idx = blockIdx.x * blockDim.x + threadIdx.x;  // 0..131071, e fast
    int h = idx >> 6, e = idx & 63;
    wt[idx] = w[e * HH + h];
}

__global__ __launch_bounds__(256) void moe_gate(
    const float* __restrict__ x, const float* __restrict__ w,
    const float* __restrict__ wt,
    float* __restrict__ out_idx, float* __restrict__ out_w,
    float* __restrict__ g_cnt, float* __restrict__ g_ssum) {

    __shared__ float part[4][M_TOK][EE];   // 32 KB partial logits
    __shared__ float bssum[EE];            // block score sums (for aux)

    const int tid  = threadIdx.x;
    const int wave = tid >> 6;
    const int lane = tid & 63;             // lane == expert in phase 1/2
    const int tok0 = blockIdx.x * M_TOK;
    const int b    = tok0 >> 12;           // token / 4096 -> batch (uniform: 32 | 4096)

    if (tid < EE) bssum[tid] = 0.f;
    __syncthreads();

    // ---------- phase 1: fp32 partial GEMV over this wave's K-range ----------
    // lane = expert, per-lane W reads coalesced via Wt; x reads are wave-uniform
    // (scalar loads), so the hot loop is pure v_fmac_f32 with a scalar operand.
    float acc[M_TOK];
#pragma unroll
    for (int t = 0; t < M_TOK; ++t) acc[t] = 0.f;

    const int k0 = wave * KC;
    const float* __restrict__ wtp = wt + (size_t)k0 * EE + lane;
    const float* __restrict__ xp  = x + (size_t)tok0 * HH + k0;

    for (int kk = 0; kk < KC; kk += 8) {
        float wr[8];
#pragma unroll
        for (int j = 0; j < 8; ++j) wr[j] = wtp[(kk + j) * EE];
#pragma unroll
        for (int t = 0; t < M_TOK; ++t) {
            const float* __restrict__ xr = xp + (size_t)t * HH + kk;
#pragma unroll
            for (int j = 0; j < 8; ++j) acc[t] = fmaf(xr[j], wr[j], acc[t]);
        }
    }
#pragma unroll
    for (int t = 0; t < M_TOK; ++t) part[wave][t][lane] = acc[t];
    __syncthreads();

    // ---------- phase 2+3: per-token softmax, top-4 (fp32), fp64 re-rank ----------
    float my_ssum = 0.f;  // sum of scores for expert=lane over this wave's tokens
    for (int ti = 0; ti < 8; ++ti) {
        const int t = wave * 8 + ti;
        float logit = part[0][t][lane] + part[1][t][lane] +
                      part[2][t][lane] + part[3][t][lane];

        // softmax scores (fp32 — only feeds aux loss, 2% tolerance)
        float m = logit;
#pragma unroll
        for (int off = 32; off; off >>= 1) m = fmaxf(m, __shfl_xor(m, off, 64));
        float p = __expf(logit - m);
        float Z = p;
#pragma unroll
        for (int off = 32; off; off >>= 1) Z += __shfl_xor(Z, off, 64);
        my_ssum += p / Z;

        // top-4 candidates by fp32 logit (tie -> lower index)
        float v = logit;
        int cand[4];
#pragma unroll
        for (int r = 0; r < 4; ++r) {
            float bv = v; int bi = lane;
#pragma unroll
            for (int off = 32; off; off >>= 1) {
                float ov = __shfl_xor(bv, off, 64);
                int   oi = __shfl_xor(bi, off, 64);
                if (ov > bv || (ov == bv && oi < bi)) { bv = ov; bi = oi; }
            }
            cand[r] = bi;
            if (lane == bi) v = -3.4e38f;
        }

        // fp64 re-rank: 4 lane-groups of 16, group c recomputes cand[c]'s logit
        const int c = lane >> 4, sub = lane & 15;
        const int e = (c == 0) ? cand[0] : (c == 1) ? cand[1]
                    : (c == 2) ? cand[2] : cand[3];
        const float* __restrict__ wp = w + (size_t)e * HH;          // original layout: coalesced in k
        const float* __restrict__ xt = x + (size_t)(tok0 + t) * HH;
        double dacc = 0.0;
        for (int j = 0; j < HH; j += 16)
            dacc += (double)wp[j + sub] * (double)xt[j + sub];
#pragma unroll
        for (int off = 8; off; off >>= 1) dacc += __shfl_xor(dacc, off, 64);
        double d0 = __shfl(dacc, 0, 64),  d1 = __shfl(dacc, 16, 64);
        double d2 = __shfl(dacc, 32, 64), d3 = __shfl(dacc, 48, 64);

        double bd[4] = {d0, d1, d2, d3};
        // ordered top-2 among (bd[r], cand[r]): desc value, tie -> asc index
        int e1 = cand[0]; double l1 = bd[0];
#pragma unroll
        for (int r = 1; r < 4; ++r)
            if (bd[r] > l1 || (bd[r] == l1 && cand[r] < e1)) { l1 = bd[r]; e1 = cand[r]; }
        int e2 = -1; double l2 = -1e300;
#pragma unroll
        for (int r = 0; r < 4; ++r) {
            if (cand[r] == e1) continue;
            if (e2 < 0 || bd[r] > l2 || (bd[r] == l2 && cand[r] < e2)) { l2 = bd[r]; e2 = cand[r]; }
        }

        // normalized top-2 weights: softmax denominator cancels
        double rr = exp(l2 - l1);            // l2 <= l1
        double w1 = 1.0 / (1.0 + rr);

        if (lane == 0) {
            const int gt = tok0 + t;
            out_idx[gt * 2]     = (float)e1;
            out_idx[gt * 2 + 1] = (float)e2;
            out_w[gt * 2]       = (float)w1;
            out_w[gt * 2 + 1]   = (float)(1.0 - w1);
            atomicAdd(&g_cnt[b * EE + e1], 1.0f);
            atomicAdd(&g_cnt[b * EE + e2], 1.0f);
        }
    }

    atomicAdd(&bssum[lane], my_ssum);
    __syncthreads();
    if (tid < EE) atomicAdd(&g_ssum[b * EE + tid], bssum[tid]);
}

// K2: aux = alpha * mean_b( sum_e ce[b,e] * mean_s(scores) )
//       = 0.01/(B * 128 * S) * sum_{b,e} cnt[b,e]*ssum[b,e]   (E/(S*K)=1/128)
__global__ void finalize(const float* __restrict__ g_cnt,
                         const float* __restrict__ g_ssum,
                         float* __restrict__ aux_out) {
    int lane = threadIdx.x;  // 64 threads
    float a = 0.f;
    for (int b = 0; b < BB; ++b) a += g_cnt[b * EE + lane] * g_ssum[b * EE + lane];
#pragma unroll
    for (int off = 32; off; off >>= 1) a += __shfl_xor(a, off, 64);
    if (lane == 0) aux_out[0] = a * (0.01f / (4.f * 128.f * 4096.f));
}

extern "C" void kernel_launch(void* const* d_in, const int* in_sizes, int n_in,
                              void* d_out, int out_size, void* d_ws, size_t ws_size,
                              hipStream_t stream) {
    const float* x = (const float*)d_in[0];   // [4,4096,2048]
    const float* w = (const float*)d_in[1];   // [64,2048]
    float* out = (float*)d_out;
    float* out_idx = out;                 // [16384*2]
    float* out_w   = out + 2 * TT;        // [16384*2]
    float* aux     = out + 4 * TT;        // [1]

    float* wt     = (float*)d_ws;         // 512 KB transposed weight
    float* g_cnt  = wt + (size_t)HH * EE; // 256 floats
    float* g_ssum = g_cnt + BB * EE;      // 256 floats

    hipMemsetAsync(g_cnt, 0, 2 * BB * EE * sizeof(float), stream);
    transpose_w<<<(HH * EE) / 256, 256, 0, stream>>>(w, wt);
    moe_gate<<<TT / M_TOK, 256, 0, stream>>>(x, w, wt, out_idx, out_w, g_cnt, g_ssum);
    finalize<<<1, 64, 0, stream>>>(g_cnt, g_ssum, aux);
}